// Round 18
// baseline (142.430 us; speedup 1.0000x reference)
//
#include <hip/hip_runtime.h>

// REConv forward. R17 lesson: with a FIXED 391-block grid, fused occupancy
// scales with threads/block (1024thr = 24 waves/CU, 512thr = 12) -- revert
// fused to R14's 1024-thread form (measured 41us). partition1 was latency-
// bound at 256 blocks (17% occ, VALUBusy 2.3%) -> 512 blocks (2 resident/CU).
// D-regions 256 nodes (391, dlocal8<<24|src24), S-regions 2048 nodes (49).
// 5 dispatches, zero scattered global atomics (only per-(block,region) claims).
// F_IN = F_OUT = 64 hardcoded.

#define THREADS 256
#define PTHREADS 512
#define NBLK_P 512
#define RSH_D 8
#define RSH_S 11
#define RBLK 256
#define CAP_D 12416u     // u32/region: raw 4096+10sig(4736) + worst pad 15*512, mult 16
#define CAP_S 50336u     // u16/region: raw 32653+10sig(34463) + worst pad 31*512, mult 32
#define SCAP 6400        // region valid-edge cap (mean 4092, sd 64)

__device__ __forceinline__ unsigned f2bf(float f) {   // RTNE f32->bf16 bits
    unsigned x = __float_as_uint(f);
    return (x + 0x7fffu + ((x >> 16) & 1u)) >> 16;
}

__global__ void initcur_kernel(unsigned* __restrict__ cursorD, unsigned* __restrict__ cursorS,
                               int nregD, int nregS) {
    int r = blockIdx.x * blockDim.x + threadIdx.x;
    if (r < nregD) cursorD[r] = (unsigned)r * CAP_D;
    if (r < nregS) cursorS[r] = (unsigned)r * CAP_S;
}

// Count -> atomic 64B-aligned window claim -> scatter -> self-pad. 512 blocks.
__global__ void partition1_kernel(const int* __restrict__ src, const int* __restrict__ dst,
                                  unsigned* __restrict__ cursorD, unsigned* __restrict__ cursorS,
                                  unsigned* __restrict__ dpack, unsigned short* __restrict__ spack,
                                  int E, int chunk, int nregD, int nregS) {
    extern __shared__ unsigned lds[];   // histD[nregD] endD[nregD] histS[nregS] endS[nregS]
    unsigned* histD = lds;
    unsigned* endD  = histD + nregD;
    unsigned* histS = endD + nregD;
    unsigned* endS  = histS + nregS;
    int t = threadIdx.x, b = blockIdx.x;
    for (int i = t; i < nregD; i += PTHREADS) histD[i] = 0u;
    for (int i = t; i < nregS; i += PTHREADS) histS[i] = 0u;
    __syncthreads();

    int beg = b * chunk, end = min(E, beg + chunk);
    for (int i = beg + t; i < end; i += PTHREADS) {
        atomicAdd(&histD[dst[i] >> RSH_D], 1u);
        atomicAdd(&histS[src[i] >> RSH_S], 1u);
    }
    __syncthreads();

    for (int r = t; r < nregD; r += PTHREADS) {
        unsigned pd = (histD[r] + 15u) & ~15u;       // u32: 16/64B
        unsigned bd = atomicAdd(&cursorD[r], pd);
        histD[r] = bd; endD[r] = bd + pd;            // histD becomes bump cursor
    }
    for (int r = t; r < nregS; r += PTHREADS) {
        unsigned ps = (histS[r] + 31u) & ~31u;       // u16: 32/64B
        unsigned bs = atomicAdd(&cursorS[r], ps);
        histS[r] = bs; endS[r] = bs + ps;
    }
    __syncthreads();

    for (int i = beg + t; i < end; i += PTHREADS) {  // chunk L2-hot from pass 1
        int s = src[i], d = dst[i];
        unsigned p = atomicAdd(&histD[d >> RSH_D], 1u);
        dpack[p] = ((unsigned)(d & (RBLK - 1)) << 24) | (unsigned)s;
        unsigned q = atomicAdd(&histS[s >> RSH_S], 1u);
        spack[q] = (unsigned short)(s & 2047);
    }
    __syncthreads();

    // Self-pad own tails (same lines as own data -> write-combines XCD-locally).
    for (int r = t; r < nregD; r += PTHREADS)
        for (unsigned i = histD[r]; i < endD[r]; ++i) dpack[i] = 0xFFFFFFFFu;
    for (int r = t; r < nregS; r += PTHREADS)
        for (unsigned i = histS[r]; i < endS[r]; ++i) spack[i] = 0xFFFFu;
}

// 49 blocks x 2048 LDS counters.
__global__ void outdeg_kernel(const unsigned short* __restrict__ spack,
                              const unsigned* __restrict__ cursorS,
                              unsigned* __restrict__ outdeg, int N) {
    __shared__ unsigned cnt[2048];
    int r = blockIdx.x, t = threadIdx.x;
    for (int i = t; i < 2048; i += PTHREADS) cnt[i] = 0u;
    __syncthreads();
    unsigned s0 = (unsigned)r * CAP_S;
    unsigned s1 = cursorS[r];                        // final cursor = window end
    for (unsigned i = s0 + t; i < s1; i += PTHREADS) {
        unsigned v = spack[i];
        if (v != 0xFFFFu) atomicAdd(&cnt[v], 1u);
    }
    __syncthreads();
    int base = r << RSH_S;
    for (int i = t; i < 2048; i += PTHREADS) {
        int node = base + i;
        if (node < N) outdeg[node] = cnt[i];
    }
}

// 8 threads per row (j-octile each).
__global__ void transform_kernel(const float* __restrict__ feat, const float* __restrict__ weight,
                                 const float* __restrict__ wtype, const int* __restrict__ tinfo,
                                 const unsigned* __restrict__ outdeg,
                                 unsigned short* __restrict__ h16, int N) {
    __shared__ float W[64 * 64];
    int t = threadIdx.x;
    const float4* w4 = (const float4*)weight;
    float4* W4 = (float4*)W;
#pragma unroll
    for (int i = 0; i < 4; ++i) W4[t + i * 256] = w4[t + i * 256];
    __syncthreads();

    int row = blockIdx.x * 32 + (t >> 3);
    if (row >= N) return;
    int jg = t & 7;

    float s = rsqrtf(fmaxf((float)outdeg[row], 1.0f)) * wtype[tinfo[row]];

    float acc[8];
#pragma unroll
    for (int j = 0; j < 8; ++j) acc[j] = 0.0f;

    const float4* frow = (const float4*)(feat + (size_t)row * 64);
    for (int k4 = 0; k4 < 16; ++k4) {
        float4 a4 = frow[k4];
#pragma unroll
        for (int kk = 0; kk < 4; ++kk) {
            float a = (kk == 0) ? a4.x : (kk == 1) ? a4.y : (kk == 2) ? a4.z : a4.w;
            const float4* wr = (const float4*)&W[(k4 * 4 + kk) * 64];
            float4 w0 = wr[jg * 2];       // 8-way same-addr broadcast: free
            float4 w1 = wr[jg * 2 + 1];
            acc[0] += a * w0.x; acc[1] += a * w0.y; acc[2] += a * w0.z; acc[3] += a * w0.w;
            acc[4] += a * w1.x; acc[5] += a * w1.y; acc[6] += a * w1.z; acc[7] += a * w1.w;
        }
    }

    unsigned* hrow = (unsigned*)(h16 + (size_t)row * 64) + jg * 4;
#pragma unroll
    for (int p = 0; p < 4; ++p) {
        unsigned u = f2bf(acc[2 * p] * s) | (f2bf(acc[2 * p + 1] * s) << 16);
        __builtin_nontemporal_store(u, hrow + p);
    }
}

// Fused per-region CSR-build (LDS) + gather. 1024 threads = 16 waves;
// each wave gathers 16 nodes. lane = rq*16+k (rq edge slot, k feature quad).
// Window read exactly twice (R16 lesson: no consumer sharding).
__global__ __launch_bounds__(1024) void fused_kernel(
        const unsigned* __restrict__ dpack, const unsigned* __restrict__ cursorD,
        const unsigned short* __restrict__ h16, const float* __restrict__ bias,
        float* __restrict__ out, int N) {
    __shared__ unsigned cnt[RBLK];
    __shared__ unsigned off[RBLK + 1];
    __shared__ unsigned cur[RBLK];
    __shared__ int slist[SCAP];
    __shared__ float sbias[64];
    int t = threadIdx.x, r = blockIdx.x;
    if (t < RBLK) cnt[t] = 0u;
    if (t < 64) sbias[t] = bias[t];
    __syncthreads();

    unsigned e0 = (unsigned)r * CAP_D;
    unsigned e1 = cursorD[r];                        // final cursor = window end

    for (unsigned i = e0 + t; i < e1; i += 1024) {
        unsigned u = dpack[i];
        if (u != 0xFFFFFFFFu) atomicAdd(&cnt[u >> 24], 1u);
    }
    __syncthreads();

    unsigned v = (t < RBLK) ? cnt[t] : 0u;
    for (int d = 1; d < RBLK; d <<= 1) {             // 256-wide Hillis-Steele
        unsigned x = (t < RBLK && t >= d) ? cnt[t - d] : 0u;
        __syncthreads();
        if (t < RBLK) cnt[t] += x;
        __syncthreads();
    }
    if (t < RBLK) {
        off[t + 1] = cnt[t];
        cur[t] = cnt[t] - v;
        if (t == 0) off[0] = 0u;
    }
    __syncthreads();

    for (unsigned i = e0 + t; i < e1; i += 1024) {   // window L2-hot from pass 1
        unsigned u = dpack[i];
        if (u != 0xFFFFFFFFu) {
            unsigned pos = atomicAdd(&cur[u >> 24], 1u);
            slist[pos] = (int)(u & 0xFFFFFFu);
        }
    }
    __syncthreads();

    int w = t >> 6, lane = t & 63;
    int rq = lane >> 4, k = lane & 15;
    for (int nl = w * 16; nl < w * 16 + 16; ++nl) {
        int node = r * RBLK + nl;
        unsigned beg = off[nl], end = off[nl + 1];
        float a0 = 0.0f, a1 = 0.0f, a2 = 0.0f, a3 = 0.0f;
        unsigned i = beg;
        for (; i + 16 <= end; i += 16) {             // 4 uint2 loads in flight
            int s0 = slist[i + rq];
            int s1 = slist[i + 4 + rq];
            int s2 = slist[i + 8 + rq];
            int s3 = slist[i + 12 + rq];
            uint2 u0 = *(const uint2*)(h16 + ((size_t)s0 << 6) + (k << 2));
            uint2 u1 = *(const uint2*)(h16 + ((size_t)s1 << 6) + (k << 2));
            uint2 u2 = *(const uint2*)(h16 + ((size_t)s2 << 6) + (k << 2));
            uint2 u3 = *(const uint2*)(h16 + ((size_t)s3 << 6) + (k << 2));
            a0 += __uint_as_float(u0.x << 16); a1 += __uint_as_float(u0.x & 0xffff0000u);
            a2 += __uint_as_float(u0.y << 16); a3 += __uint_as_float(u0.y & 0xffff0000u);
            a0 += __uint_as_float(u1.x << 16); a1 += __uint_as_float(u1.x & 0xffff0000u);
            a2 += __uint_as_float(u1.y << 16); a3 += __uint_as_float(u1.y & 0xffff0000u);
            a0 += __uint_as_float(u2.x << 16); a1 += __uint_as_float(u2.x & 0xffff0000u);
            a2 += __uint_as_float(u2.y << 16); a3 += __uint_as_float(u2.y & 0xffff0000u);
            a0 += __uint_as_float(u3.x << 16); a1 += __uint_as_float(u3.x & 0xffff0000u);
            a2 += __uint_as_float(u3.y << 16); a3 += __uint_as_float(u3.y & 0xffff0000u);
        }
        for (; i + 8 <= end; i += 8) {
            int s0 = slist[i + rq];
            int s1 = slist[i + 4 + rq];
            uint2 u0 = *(const uint2*)(h16 + ((size_t)s0 << 6) + (k << 2));
            uint2 u1 = *(const uint2*)(h16 + ((size_t)s1 << 6) + (k << 2));
            a0 += __uint_as_float(u0.x << 16); a1 += __uint_as_float(u0.x & 0xffff0000u);
            a2 += __uint_as_float(u0.y << 16); a3 += __uint_as_float(u0.y & 0xffff0000u);
            a0 += __uint_as_float(u1.x << 16); a1 += __uint_as_float(u1.x & 0xffff0000u);
            a2 += __uint_as_float(u1.y << 16); a3 += __uint_as_float(u1.y & 0xffff0000u);
        }
        for (; i < end; i += 4) {
            unsigned j = i + rq;
            if (j < end) {
                int s = slist[j];
                uint2 u = *(const uint2*)(h16 + ((size_t)s << 6) + (k << 2));
                a0 += __uint_as_float(u.x << 16); a1 += __uint_as_float(u.x & 0xffff0000u);
                a2 += __uint_as_float(u.y << 16); a3 += __uint_as_float(u.y & 0xffff0000u);
            }
        }

        a0 += __shfl_xor(a0, 16, 64);  a0 += __shfl_xor(a0, 32, 64);
        a1 += __shfl_xor(a1, 16, 64);  a1 += __shfl_xor(a1, 32, 64);
        a2 += __shfl_xor(a2, 16, 64);  a2 += __shfl_xor(a2, 32, 64);
        a3 += __shfl_xor(a3, 16, 64);  a3 += __shfl_xor(a3, 32, 64);

        if (node < N && rq == 0) {
            float sc = rsqrtf(fmaxf((float)(end - beg), 1.0f));
            float4 b = ((const float4*)sbias)[k];
            float* op = out + ((size_t)node << 6) + (k << 2);
            __builtin_nontemporal_store(a0 * sc + b.x, op + 0);
            __builtin_nontemporal_store(a1 * sc + b.y, op + 1);
            __builtin_nontemporal_store(a2 * sc + b.z, op + 2);
            __builtin_nontemporal_store(a3 * sc + b.w, op + 3);
        }
    }
}

extern "C" void kernel_launch(void* const* d_in, const int* in_sizes, int n_in,
                              void* d_out, int out_size, void* d_ws, size_t ws_size,
                              hipStream_t stream) {
    const float* feat   = (const float*)d_in[0];
    const float* weight = (const float*)d_in[1];
    const float* wtype  = (const float*)d_in[2];
    const float* bias   = (const float*)d_in[3];
    const int*   src    = (const int*)d_in[4];
    const int*   dst    = (const int*)d_in[5];
    const int*   tinfo  = (const int*)d_in[6];

    int E = in_sizes[4];
    int N = in_sizes[6];
    float* out = (float*)d_out;

    int nregD = (N + RBLK - 1) >> RSH_D;           // 391
    int nregS = (N + 2047) >> RSH_S;               // 49
    int pchunk = (E + NBLK_P - 1) / NBLK_P;        // 3125

    // Workspace: dpack 19.4MB | spack 4.9MB | h16 12.8MB | cursors | outdeg (~38MB)
    char* ws = (char*)d_ws;
    unsigned* dpack       = (unsigned*)ws;          ws += (size_t)nregD * CAP_D * sizeof(unsigned);
    unsigned short* spack = (unsigned short*)ws;    ws += (size_t)nregS * CAP_S * sizeof(unsigned short);
    unsigned short* h16   = (unsigned short*)ws;    ws += (size_t)N * 64 * sizeof(unsigned short);
    unsigned* cursorD     = (unsigned*)ws;          ws += (size_t)nregD * sizeof(unsigned);
    unsigned* cursorS     = (unsigned*)ws;          ws += (size_t)nregS * sizeof(unsigned);
    unsigned* outdeg      = (unsigned*)ws;          ws += (size_t)N * sizeof(unsigned);

    initcur_kernel<<<(nregD + THREADS - 1) / THREADS, THREADS, 0, stream>>>(cursorD, cursorS,
                                                                            nregD, nregS);

    size_t part_lds = (size_t)(2 * nregD + 2 * nregS) * sizeof(unsigned);
    partition1_kernel<<<NBLK_P, PTHREADS, part_lds, stream>>>(
        src, dst, cursorD, cursorS, dpack, spack, E, pchunk, nregD, nregS);

    outdeg_kernel<<<nregS, PTHREADS, 0, stream>>>(spack, cursorS, outdeg, N);

    transform_kernel<<<(N + 31) / 32, THREADS, 0, stream>>>(
        feat, weight, wtype, tinfo, outdeg, h16, N);

    fused_kernel<<<nregD, 1024, 0, stream>>>(dpack, cursorD, h16, bias, out, N);
}

// Round 19
// 111.781 us; speedup vs baseline: 1.2742x; 1.2742x over previous
//
#include <hip/hip_runtime.h>

// REConv forward — exact R14 structure (best measured: 114.8us), with ONE
// change: partition1 at 1024 threads/block (was 512). R15 profile showed it
// latency-bound (VALUBusy 2.3%, 17% occ); same 256 blocks -> identical pad
// layout (CAP_D/CAP_S unchanged, proven 75MB fused FETCH), 2x resident waves.
// Pipeline: initcur -> partition1(count+claim+scatter+self-pad) -> outdeg ->
//           transform(8thr/row) -> fused(LDS CSR build + gather, 1024thr).
// F_IN = F_OUT = 64 hardcoded.

#define THREADS 256
#define PART_T 1024       // partition block size (R15: 512 -> latency-bound)
#define NCHUNKB 256       // partition blocks
#define RSH 8
#define RBLK 256
#define CAP_D 8704u       // u32 per region: raw 4096+10sig + worst pad 15*256 (mult of 16)
#define CAP_S 12800u      // u16 per region: raw 4096+10sig + worst pad 31*256 (mult of 32)
#define SCAP 6400         // region valid-edge cap (mean 4096, sd 64)

__device__ __forceinline__ unsigned f2bf(float f) {   // RTNE f32->bf16 bits
    unsigned x = __float_as_uint(f);
    return (x + 0x7fffu + ((x >> 16) & 1u)) >> 16;
}

__global__ void initcur_kernel(unsigned* __restrict__ cursorD,
                               unsigned* __restrict__ cursorS, int nreg) {
    int r = blockIdx.x * blockDim.x + threadIdx.x;
    if (r < nreg) {
        cursorD[r] = (unsigned)r * CAP_D;
        cursorS[r] = (unsigned)r * CAP_S;
    }
}

// One pass: LDS count -> atomic window claim -> scatter -> self-pad. 1024 thr.
__global__ __launch_bounds__(1024) void partition1_kernel(
        const int* __restrict__ src, const int* __restrict__ dst,
        unsigned* __restrict__ cursorD, unsigned* __restrict__ cursorS,
        unsigned* __restrict__ dpack, unsigned short* __restrict__ spack,
        int E, int chunk, int nreg) {
    extern __shared__ unsigned lds[];   // histD | histS | endD | endS  (histX reused as bump cursor)
    unsigned* histD = lds;
    unsigned* histS = histD + nreg;
    unsigned* endD  = histS + nreg;
    unsigned* endS  = endD + nreg;
    int t = threadIdx.x, b = blockIdx.x;
    for (int i = t; i < 2 * nreg; i += PART_T) lds[i] = 0u;
    __syncthreads();

    int beg = b * chunk, end = min(E, beg + chunk);
    for (int i = beg + t; i < end; i += PART_T) {
        atomicAdd(&histD[dst[i] >> RSH], 1u);
        atomicAdd(&histS[src[i] >> RSH], 1u);
    }
    __syncthreads();

    for (int r = t; r < nreg; r += PART_T) {
        unsigned pd = (histD[r] + 15u) & ~15u;     // u32: 16/64B
        unsigned ps = (histS[r] + 31u) & ~31u;     // u16: 32/64B
        unsigned bd = atomicAdd(&cursorD[r], pd);  // exclusive 64B-aligned sub-window
        unsigned bs = atomicAdd(&cursorS[r], ps);
        histD[r] = bd; endD[r] = bd + pd;          // histX becomes bump cursor
        histS[r] = bs; endS[r] = bs + ps;
    }
    __syncthreads();

    for (int i = beg + t; i < end; i += PART_T) {     // chunk L2-hot from pass 1
        int s = src[i], d = dst[i];
        unsigned p = atomicAdd(&histD[d >> RSH], 1u);
        dpack[p] = ((unsigned)(d & (RBLK - 1)) << 24) | (unsigned)s;
        unsigned q = atomicAdd(&histS[s >> RSH], 1u);
        spack[q] = (unsigned short)(s & (RBLK - 1));
    }
    __syncthreads();

    // Self-pad own tails (same lines as own data -> write-combines XCD-locally).
    for (int r = t; r < nreg; r += PART_T) {
        for (unsigned i = histD[r]; i < endD[r]; ++i) dpack[i] = 0xFFFFFFFFu;
        for (unsigned i = histS[r]; i < endS[r]; ++i) spack[i] = 0xFFFFu;
    }
}

__global__ void outdeg_kernel(const unsigned short* __restrict__ spack,
                              const unsigned* __restrict__ cursorS,
                              unsigned* __restrict__ outdeg, int N) {
    __shared__ unsigned cnt[RBLK];
    int r = blockIdx.x, t = threadIdx.x;
    cnt[t] = 0u;
    __syncthreads();
    unsigned s0 = (unsigned)r * CAP_S;
    unsigned s1 = cursorS[r];                      // final cursor = window end
    for (unsigned i = s0 + t; i < s1; i += THREADS) {
        unsigned v = spack[i];
        if (v != 0xFFFFu) atomicAdd(&cnt[v], 1u);
    }
    __syncthreads();
    int node = r * RBLK + t;
    if (node < N) outdeg[node] = cnt[t];
}

// 8 threads per row (j-octile each).
__global__ void transform_kernel(const float* __restrict__ feat, const float* __restrict__ weight,
                                 const float* __restrict__ wtype, const int* __restrict__ tinfo,
                                 const unsigned* __restrict__ outdeg,
                                 unsigned short* __restrict__ h16, int N) {
    __shared__ float W[64 * 64];
    int t = threadIdx.x;
    const float4* w4 = (const float4*)weight;
    float4* W4 = (float4*)W;
#pragma unroll
    for (int i = 0; i < 4; ++i) W4[t + i * 256] = w4[t + i * 256];
    __syncthreads();

    int row = blockIdx.x * 32 + (t >> 3);
    if (row >= N) return;
    int jg = t & 7;

    float s = rsqrtf(fmaxf((float)outdeg[row], 1.0f)) * wtype[tinfo[row]];

    float acc[8];
#pragma unroll
    for (int j = 0; j < 8; ++j) acc[j] = 0.0f;

    const float4* frow = (const float4*)(feat + (size_t)row * 64);
    for (int k4 = 0; k4 < 16; ++k4) {
        float4 a4 = frow[k4];
#pragma unroll
        for (int kk = 0; kk < 4; ++kk) {
            float a = (kk == 0) ? a4.x : (kk == 1) ? a4.y : (kk == 2) ? a4.z : a4.w;
            const float4* wr = (const float4*)&W[(k4 * 4 + kk) * 64];
            float4 w0 = wr[jg * 2];       // 8-way same-addr broadcast: free
            float4 w1 = wr[jg * 2 + 1];
            acc[0] += a * w0.x; acc[1] += a * w0.y; acc[2] += a * w0.z; acc[3] += a * w0.w;
            acc[4] += a * w1.x; acc[5] += a * w1.y; acc[6] += a * w1.z; acc[7] += a * w1.w;
        }
    }

    unsigned* hrow = (unsigned*)(h16 + (size_t)row * 64) + jg * 4;
#pragma unroll
    for (int p = 0; p < 4; ++p) {
        unsigned u = f2bf(acc[2 * p] * s) | (f2bf(acc[2 * p + 1] * s) << 16);
        __builtin_nontemporal_store(u, hrow + p);
    }
}

// Fused per-region CSR-build (in LDS) + gather. 1024 threads = 16 waves;
// each wave gathers 16 nodes. lane = rq*16+k (rq edge slot, k feature quad).
// Window read exactly twice (R16 lesson: no consumer sharding).
__global__ __launch_bounds__(1024) void fused_kernel(
        const unsigned* __restrict__ dpack, const unsigned* __restrict__ cursorD,
        const unsigned short* __restrict__ h16, const float* __restrict__ bias,
        float* __restrict__ out, int N) {
    __shared__ unsigned cnt[RBLK];
    __shared__ unsigned off[RBLK + 1];
    __shared__ unsigned cur[RBLK];
    __shared__ int slist[SCAP];
    __shared__ float sbias[64];
    int t = threadIdx.x, r = blockIdx.x;
    if (t < RBLK) cnt[t] = 0u;
    if (t < 64) sbias[t] = bias[t];
    __syncthreads();

    unsigned e0 = (unsigned)r * CAP_D;
    unsigned e1 = cursorD[r];                      // final cursor = window end

    for (unsigned i = e0 + t; i < e1; i += 1024) {
        unsigned u = dpack[i];
        if (u != 0xFFFFFFFFu) atomicAdd(&cnt[u >> 24], 1u);
    }
    __syncthreads();

    unsigned v = (t < RBLK) ? cnt[t] : 0u;
    for (int d = 1; d < RBLK; d <<= 1) {             // 256-wide Hillis-Steele
        unsigned x = (t < RBLK && t >= d) ? cnt[t - d] : 0u;
        __syncthreads();
        if (t < RBLK) cnt[t] += x;
        __syncthreads();
    }
    if (t < RBLK) {
        off[t + 1] = cnt[t];
        cur[t] = cnt[t] - v;
        if (t == 0) off[0] = 0u;
    }
    __syncthreads();

    for (unsigned i = e0 + t; i < e1; i += 1024) {   // window L2-hot from pass 1
        unsigned u = dpack[i];
        if (u != 0xFFFFFFFFu) {
            unsigned pos = atomicAdd(&cur[u >> 24], 1u);
            slist[pos] = (int)(u & 0xFFFFFFu);
        }
    }
    __syncthreads();

    int w = t >> 6, lane = t & 63;
    int rq = lane >> 4, k = lane & 15;
    for (int nl = w * 16; nl < w * 16 + 16; ++nl) {
        int node = r * RBLK + nl;
        unsigned beg = off[nl], end = off[nl + 1];
        float a0 = 0.0f, a1 = 0.0f, a2 = 0.0f, a3 = 0.0f;
        unsigned i = beg;
        for (; i + 16 <= end; i += 16) {             // 4 uint2 loads in flight
            int s0 = slist[i + rq];
            int s1 = slist[i + 4 + rq];
            int s2 = slist[i + 8 + rq];
            int s3 = slist[i + 12 + rq];
            uint2 u0 = *(const uint2*)(h16 + ((size_t)s0 << 6) + (k << 2));
            uint2 u1 = *(const uint2*)(h16 + ((size_t)s1 << 6) + (k << 2));
            uint2 u2 = *(const uint2*)(h16 + ((size_t)s2 << 6) + (k << 2));
            uint2 u3 = *(const uint2*)(h16 + ((size_t)s3 << 6) + (k << 2));
            a0 += __uint_as_float(u0.x << 16); a1 += __uint_as_float(u0.x & 0xffff0000u);
            a2 += __uint_as_float(u0.y << 16); a3 += __uint_as_float(u0.y & 0xffff0000u);
            a0 += __uint_as_float(u1.x << 16); a1 += __uint_as_float(u1.x & 0xffff0000u);
            a2 += __uint_as_float(u1.y << 16); a3 += __uint_as_float(u1.y & 0xffff0000u);
            a0 += __uint_as_float(u2.x << 16); a1 += __uint_as_float(u2.x & 0xffff0000u);
            a2 += __uint_as_float(u2.y << 16); a3 += __uint_as_float(u2.y & 0xffff0000u);
            a0 += __uint_as_float(u3.x << 16); a1 += __uint_as_float(u3.x & 0xffff0000u);
            a2 += __uint_as_float(u3.y << 16); a3 += __uint_as_float(u3.y & 0xffff0000u);
        }
        for (; i + 8 <= end; i += 8) {
            int s0 = slist[i + rq];
            int s1 = slist[i + 4 + rq];
            uint2 u0 = *(const uint2*)(h16 + ((size_t)s0 << 6) + (k << 2));
            uint2 u1 = *(const uint2*)(h16 + ((size_t)s1 << 6) + (k << 2));
            a0 += __uint_as_float(u0.x << 16); a1 += __uint_as_float(u0.x & 0xffff0000u);
            a2 += __uint_as_float(u0.y << 16); a3 += __uint_as_float(u0.y & 0xffff0000u);
            a0 += __uint_as_float(u1.x << 16); a1 += __uint_as_float(u1.x & 0xffff0000u);
            a2 += __uint_as_float(u1.y << 16); a3 += __uint_as_float(u1.y & 0xffff0000u);
        }
        for (; i < end; i += 4) {
            unsigned j = i + rq;
            if (j < end) {
                int s = slist[j];
                uint2 u = *(const uint2*)(h16 + ((size_t)s << 6) + (k << 2));
                a0 += __uint_as_float(u.x << 16); a1 += __uint_as_float(u.x & 0xffff0000u);
                a2 += __uint_as_float(u.y << 16); a3 += __uint_as_float(u.y & 0xffff0000u);
            }
        }

        a0 += __shfl_xor(a0, 16, 64);  a0 += __shfl_xor(a0, 32, 64);
        a1 += __shfl_xor(a1, 16, 64);  a1 += __shfl_xor(a1, 32, 64);
        a2 += __shfl_xor(a2, 16, 64);  a2 += __shfl_xor(a2, 32, 64);
        a3 += __shfl_xor(a3, 16, 64);  a3 += __shfl_xor(a3, 32, 64);

        if (node < N && rq == 0) {
            float sc = rsqrtf(fmaxf((float)(end - beg), 1.0f));
            float4 b = ((const float4*)sbias)[k];
            float* op = out + ((size_t)node << 6) + (k << 2);
            __builtin_nontemporal_store(a0 * sc + b.x, op + 0);
            __builtin_nontemporal_store(a1 * sc + b.y, op + 1);
            __builtin_nontemporal_store(a2 * sc + b.z, op + 2);
            __builtin_nontemporal_store(a3 * sc + b.w, op + 3);
        }
    }
}

extern "C" void kernel_launch(void* const* d_in, const int* in_sizes, int n_in,
                              void* d_out, int out_size, void* d_ws, size_t ws_size,
                              hipStream_t stream) {
    const float* feat   = (const float*)d_in[0];
    const float* weight = (const float*)d_in[1];
    const float* wtype  = (const float*)d_in[2];
    const float* bias   = (const float*)d_in[3];
    const int*   src    = (const int*)d_in[4];
    const int*   dst    = (const int*)d_in[5];
    const int*   tinfo  = (const int*)d_in[6];

    int E = in_sizes[4];
    int N = in_sizes[6];
    float* out = (float*)d_out;

    int nreg   = (N + RBLK - 1) >> RSH;            // 391
    int pchunk = (E + NCHUNKB - 1) / NCHUNKB;      // 6250

    // Workspace: dpack 13.6MB | spack 10.0MB | h16 12.8MB | cursors | outdeg (~37MB)
    char* ws = (char*)d_ws;
    unsigned* dpack       = (unsigned*)ws;          ws += (size_t)nreg * CAP_D * sizeof(unsigned);
    unsigned short* spack = (unsigned short*)ws;    ws += (size_t)nreg * CAP_S * sizeof(unsigned short);
    unsigned short* h16   = (unsigned short*)ws;    ws += (size_t)N * 64 * sizeof(unsigned short);
    unsigned* cursorD     = (unsigned*)ws;          ws += (size_t)nreg * sizeof(unsigned);
    unsigned* cursorS     = (unsigned*)ws;          ws += (size_t)nreg * sizeof(unsigned);
    unsigned* outdeg      = (unsigned*)ws;          ws += (size_t)N * sizeof(unsigned);

    initcur_kernel<<<(nreg + THREADS - 1) / THREADS, THREADS, 0, stream>>>(cursorD, cursorS, nreg);

    size_t part_lds = (size_t)4 * nreg * sizeof(unsigned);
    partition1_kernel<<<NCHUNKB, PART_T, part_lds, stream>>>(
        src, dst, cursorD, cursorS, dpack, spack, E, pchunk, nreg);

    outdeg_kernel<<<nreg, THREADS, 0, stream>>>(spack, cursorS, outdeg, N);

    transform_kernel<<<(N + 31) / 32, THREADS, 0, stream>>>(
        feat, weight, wtype, tinfo, outdeg, h16, N);

    fused_kernel<<<nreg, 1024, 0, stream>>>(dpack, cursorD, h16, bias, out, N);
}